// Round 7
// baseline (79.481 us; speedup 1.0000x reference)
//
#include <hip/hip_runtime.h>
#include <hip/hip_bf16.h>
#include <cstdint>
#include <cstddef>

#define NUM_CLASS 1000
#define NPAD      1024
#define LOW_DIM   128
#define B_UPD     1024
#define B_SIM     65536

typedef short bf16x8 __attribute__((ext_vector_type(8)));
typedef float f32x4  __attribute__((ext_vector_type(4)));

__device__ __forceinline__ unsigned short f2bf(float f) {
  union { float f; unsigned u; } a; a.f = f;
  unsigned u = a.u;
  return (unsigned short)((u + 0x7fffu + ((u >> 16) & 1u)) >> 16);  // RNE
}

// ---------- kernel 1: per-class EMA (ballot scan) + L2 norm -> fragment-swizzled bf16 ----------
// Updates to different labels commute, so per-class in-order processing
// reproduces the reference lax.scan exactly.
// Output layout = MFMA B-fragment order so GEMM B loads are coalesced 1KB
// wave reads:
//   slot[((g*4 + kk)*64 + l) * 8 + e]  (ushort units)
//   holds logical B[row = g*16 + (l&15)][k = kk*32 + (l>>4)*8 + e]
__global__ void proto_update_kernel(const float* __restrict__ pred_feat,
                                    const int*   __restrict__ labels,
                                    const float* __restrict__ protos_in,
                                    unsigned short* __restrict__ protos_sw) {
  int c = blockIdx.x;    // 0..1023
  int d = threadIdx.x;   // 0..127
  float p = 0.0f;
  if (c < NUM_CLASS) {
    p = protos_in[c * LOW_DIM + d];
    #pragma unroll 4
    for (int k = 0; k < B_UPD / 64; ++k) {
      int lab = labels[k * 64 + (d & 63)];
      unsigned long long m = __ballot(lab == c);   // wave-uniform
      while (m) {
        int b = __builtin_ctzll(m);
        m &= (m - 1);
        p = 0.99f * p + 0.01f * pred_feat[(size_t)(k * 64 + b) * LOW_DIM + d];
      }
    }
  }
  float sq = p * p;
  #pragma unroll
  for (int o = 1; o < 64; o <<= 1) sq += __shfl_xor(sq, o, 64);
  __shared__ float wsum[2];
  if ((d & 63) == 0) wsum[d >> 6] = sq;
  __syncthreads();
  float total = wsum[0] + wsum[1];
  unsigned short v = f2bf(p / fmaxf(sqrtf(total), 1e-12f));  // c>=1000 -> 0
  int g = c >> 4, r = c & 15, kk = d >> 5, j = (d >> 3) & 3, e = d & 7;
  protos_sw[(size_t)((g * 4 + kk) * 64 + j * 16 + r) * 8 + e] = v;
}

// ---------- kernel 2: C[65536,1000] = A(f32->bf16) @ B^T, BM=32 x full-N ----------
// R6 structure with the epilogue LDS-transpose REMOVED: acc stored directly
// in MFMA C-layout. Per (m,n,r) a 16-lane group writes 16 consecutive cols
// = one 64B segment (col byte base 512*w + 64*n). This deletes the post-K
// __syncthreads (epilogue is pure per-wave -> waves desynchronize, stores
// stream continuously), drops ~550 cyc/wave of LDS work, and shrinks LDS to
// 8 KB. 8 waves; wave w owns 32 rows x cols [w*128, w*128+128).
#define BM   32
#define TPB2 512

__global__ __launch_bounds__(TPB2, 4)
void gemm_sim_kernel(const float* __restrict__ A,
                     const unsigned short* __restrict__ Bsw,
                     float* __restrict__ C) {
  __shared__ alignas(16) unsigned char Als[BM * 256];   // 8 KB swizzled A
  int t  = threadIdx.x;
  int m0 = blockIdx.x * BM;

  // ---- stage A: 32 rows x 128 f32 -> bf16, XOR-swizzled (rows 256 B) ----
  {
    int row = t >> 4, c8 = t & 15;   // 512 threads = 32 rows x 16 slots
    const float4* s = reinterpret_cast<const float4*>(A + (size_t)(m0 + row) * LOW_DIM + c8 * 8);
    float4 v0 = s[0], v1 = s[1];
    uint4 q;
    q.x = f2bf(v0.x) | ((unsigned)f2bf(v0.y) << 16);
    q.y = f2bf(v0.z) | ((unsigned)f2bf(v0.w) << 16);
    q.z = f2bf(v1.x) | ((unsigned)f2bf(v1.y) << 16);
    q.w = f2bf(v1.z) | ((unsigned)f2bf(v1.w) << 16);
    *reinterpret_cast<uint4*>(Als + row * 256 + ((c8 * 16) ^ ((row & 7) << 4))) = q;
  }
  __syncthreads();

  int lane = t & 63;
  int w    = t >> 6;
  int lr   = lane & 15;
  int lkb  = (lane >> 4) * 16;

  f32x4 acc[2][8];
  #pragma unroll
  for (int m = 0; m < 2; ++m)
    #pragma unroll
    for (int n = 0; n < 8; ++n)
      acc[m][n] = (f32x4){0.f, 0.f, 0.f, 0.f};

  #pragma unroll
  for (int kk = 0; kk < 4; ++kk) {             // K = 4 x 32
    int kb = kk * 64 + lkb;
    bf16x8 af[2];
    #pragma unroll
    for (int m = 0; m < 2; ++m) {
      int row = m * 16 + lr;
      af[m] = *reinterpret_cast<const bf16x8*>(Als + row * 256 + (kb ^ ((row & 7) << 4)));
    }
    #pragma unroll
    for (int n = 0; n < 8; ++n) {
      int g = w * 8 + n;                       // 16-row group of B
      bf16x8 bf = *reinterpret_cast<const bf16x8*>(
          Bsw + ((size_t)(g * 4 + kk) * 64 + lane) * 8);   // coalesced 1KB/wave
      #pragma unroll
      for (int m = 0; m < 2; ++m)
        acc[m][n] = __builtin_amdgcn_mfma_f32_16x16x32_bf16(af[m], bf, acc[m][n], 0, 0, 0);
    }
  }

  // ---- direct epilogue: no barrier, no LDS; per-wave streaming stores ----
  // C/D layout: col = lane&15, row = (lane>>4)*4 + r. One (m,n,r) store =
  // four 64B segments (one per 16-lane group), all within-row aligned.
  int colbase = w * 128 + lr;                  // this lane's column for all n
  #pragma unroll
  for (int m = 0; m < 2; ++m) {
    size_t rowbase = (size_t)(m0 + m * 16 + (lane >> 4) * 4) * NUM_CLASS;
    #pragma unroll
    for (int r = 0; r < 4; ++r) {
      float* Crow = C + rowbase + (size_t)r * NUM_CLASS + colbase;
      #pragma unroll
      for (int n = 0; n < 8; ++n) {
        int col = colbase + n * 16;
        if (col < NUM_CLASS)                   // only wave 7's last group masked
          Crow[n * 16] = acc[m][n][r];
      }
    }
  }
}

extern "C" void kernel_launch(void* const* d_in, const int* in_sizes, int n_in,
                              void* d_out, int out_size, void* d_ws, size_t ws_size,
                              hipStream_t stream) {
  const float* pred_feat = (const float*)d_in[0];   // [1024,128]
  const int*   labels    = (const int*)d_in[1];     // [1024]
  const float* protos    = (const float*)d_in[2];   // [1000,128]
  const float* feat      = (const float*)d_in[3];   // [65536,128]
  float* out = (float*)d_out;                       // [65536,1000]

  unsigned short* protos_sw = (unsigned short*)d_ws;  // 256 KB fragment-swizzled

  proto_update_kernel<<<NPAD, 128, 0, stream>>>(pred_feat, labels, protos, protos_sw);
  gemm_sim_kernel<<<B_SIM / BM, TPB2, 0, stream>>>(feat, protos_sw, out);
}